// Round 8
// baseline (192.306 us; speedup 1.0000x reference)
//
#include <hip/hip_runtime.h>
#include <hip/hip_bf16.h>
#include <math.h>

typedef __bf16 bf16;
typedef __attribute__((ext_vector_type(8))) __bf16 bf16x8;
typedef __attribute__((ext_vector_type(4))) short s16x4;
typedef __attribute__((ext_vector_type(4))) float f32x4;

#define EMB 768
#define T_SEQ 1024
#define HEADS 12
#define HDIM 64

// ---------------- fused prep: x fp32->bf16, W_attn / W_proj transpose+cvt ----------------
__global__ void prep_k(const float* __restrict__ x, bf16* __restrict__ xb,
                       const float* __restrict__ Wa, bf16* __restrict__ Wta,
                       const float* __restrict__ Wp, bf16* __restrict__ Wtp) {
  __shared__ float tile[32][33];
  const int blk = blockIdx.x, tid = threadIdx.x;
  if (blk < 3072) {
    const size_t i = (size_t)blk * 256 + tid;
    const float4* p = (const float4*)(x + i * 8);
    const float4 a = p[0], b = p[1];
    bf16x8 v;
    v[0] = (bf16)a.x; v[1] = (bf16)a.y; v[2] = (bf16)a.z; v[3] = (bf16)a.w;
    v[4] = (bf16)b.x; v[5] = (bf16)b.y; v[6] = (bf16)b.z; v[7] = (bf16)b.w;
    *(bf16x8*)(xb + i * 8) = v;
    return;
  }
  const float* in;
  bf16* out;
  int C, t;
  if (blk < 3072 + 1728) { in = Wa; out = Wta; C = 3 * EMB; t = blk - 3072; }
  else                   { in = Wp; out = Wtp; C = EMB;     t = blk - 4800; }
  const int R = EMB;
  const int c0 = (t % (C / 32)) * 32, r0 = (t / (C / 32)) * 32;
  const int tx = tid & 31, ty = tid >> 5;
  for (int i = ty; i < 32; i += 8)
    tile[i][tx] = in[(size_t)(r0 + i) * C + c0 + tx];
  __syncthreads();
  for (int i = ty; i < 32; i += 8)
    out[(size_t)(c0 + i) * R + r0 + tx] = (bf16)tile[tx][i];
}

// ---------------- GEMM: C[M][N] = A[M][K] @ Bt[N][K]^T + bias ----------------
// BK=64 (2x32 slices), double-buffered LDS, ONE barrier per K-iteration:
//   barrier -> issue async stage(next) -> compute(cur).
// At the barrier, outstanding loads are cur's, issued one full compute-phase ago.
template <int MODE>
__global__ __launch_bounds__(256) void gemm_bt(
    const bf16* __restrict__ A, const bf16* __restrict__ Bt, const float* __restrict__ bias,
    bf16* __restrict__ Cb, float* __restrict__ Cf, int M, int N, int K) {
  __shared__ __align__(16) bf16 SA[2][2][128 * 32];
  __shared__ __align__(16) bf16 SB[2][2][128 * 32];
  const int lane = threadIdx.x & 63;
  const int wave = threadIdx.x >> 6;
  const int quad = lane >> 4, lc = lane & 15;
  const int m0 = blockIdx.y * 128, n0 = blockIdx.x * 128;
  const int wm = (wave >> 1) * 64, wn = (wave & 1) * 64;
  const int srow = lane >> 2;        // 0..15 (row within 16-row chunk)
  const int skk = (lane & 3) * 8;    // 0,8,16,24 (k offset within slice)

  const bf16* gA0 = A + (size_t)(m0 + srow) * K + skk;
  const bf16* gB0 = Bt + (size_t)(n0 + srow) * K + skk;

  auto stage = [&](int p, int k0) {
#pragma unroll
    for (int c = wave; c < 8; c += 4) {
      const bf16* gA = gA0 + (size_t)c * 16 * K + k0;
      const bf16* gB = gB0 + (size_t)c * 16 * K + k0;
      __builtin_amdgcn_global_load_lds((const __attribute__((address_space(1))) void*)gA,
                                       (__attribute__((address_space(3))) void*)(&SA[p][0][c * 512]), 16, 0, 0);
      __builtin_amdgcn_global_load_lds((const __attribute__((address_space(1))) void*)(gA + 32),
                                       (__attribute__((address_space(3))) void*)(&SA[p][1][c * 512]), 16, 0, 0);
      __builtin_amdgcn_global_load_lds((const __attribute__((address_space(1))) void*)gB,
                                       (__attribute__((address_space(3))) void*)(&SB[p][0][c * 512]), 16, 0, 0);
      __builtin_amdgcn_global_load_lds((const __attribute__((address_space(1))) void*)(gB + 32),
                                       (__attribute__((address_space(3))) void*)(&SB[p][1][c * 512]), 16, 0, 0);
    }
  };

  f32x4 zero = {0.f, 0.f, 0.f, 0.f};
  f32x4 acc[4][4];
#pragma unroll
  for (int i = 0; i < 4; ++i)
#pragma unroll
    for (int j = 0; j < 4; ++j) acc[i][j] = zero;

  stage(0, 0);
  const int nit = K >> 6;  // 12
  for (int i = 0; i < nit; ++i) {
    __syncthreads();                      // drains cur loads (in flight since last iter)
    if (i + 1 < nit) stage((i + 1) & 1, (i + 1) << 6);  // async prefetch, no wait
    const int p = i & 1;
#pragma unroll
    for (int s = 0; s < 2; ++s) {
      bf16x8 af[4], bfr[4];
#pragma unroll
      for (int t = 0; t < 4; ++t) af[t] = *(const bf16x8*)&SA[p][s][(wm + t * 16 + lc) * 32 + quad * 8];
#pragma unroll
      for (int t = 0; t < 4; ++t) bfr[t] = *(const bf16x8*)&SB[p][s][(wn + t * 16 + lc) * 32 + quad * 8];
#pragma unroll
      for (int tm = 0; tm < 4; ++tm)
#pragma unroll
        for (int tn = 0; tn < 4; ++tn)
          acc[tm][tn] = __builtin_amdgcn_mfma_f32_16x16x32_bf16(af[tm], bfr[tn], acc[tm][tn], 0, 0, 0);
    }
  }

#pragma unroll
  for (int tm = 0; tm < 4; ++tm) {
#pragma unroll
    for (int tn = 0; tn < 4; ++tn) {
      const int col = n0 + wn + tn * 16 + lc;
      const float bv = bias[col];
#pragma unroll
      for (int r = 0; r < 4; ++r) {
        const int row = m0 + wm + tm * 16 + quad * 4 + r;
        const float v = acc[tm][tn][r] + bv;
        if (MODE == 0) Cb[(size_t)row * N + col] = (bf16)v;
        else           Cf[(size_t)row * N + col] = v;
      }
    }
  }
}

// ---------------- causal flash attention, transposed-score, no-max exp2 softmax ----------------
// qkv: [B*T][2304] rows (q|k|v); outb: [B*T][768]
__global__ __launch_bounds__(512, 4) void attn_k(const bf16* __restrict__ qkv,
                                                 bf16* __restrict__ outb) {
  __shared__ __align__(16) bf16 Qs[128][72];   // [q][d], pre-scaled by log2(e)/8; reused for O out
  __shared__ __align__(16) bf16 Ks[128][72];   // [key][d]
  __shared__ __align__(16) bf16 Vt[64][132];   // V^T [d][key]

  const int lane = threadIdx.x & 63;
  const int wave = threadIdx.x >> 6;           // 0..7, each owns 16 q rows
  const int quad = lane >> 4, lc = lane & 15;
  const int flat = blockIdx.x;
  const int bh = flat % (HEADS * 8);
  const int qt = 7 - flat / (HEADS * 8);
  const int h = bh % HEADS;
  const int b = bh / HEADS;
  const int q0 = qt * 128;
  const size_t rowB = (size_t)b * T_SEQ;
  const int hoff = h * HDIM;
  const int tid = threadIdx.x;
  const float C1 = 0.125f * 1.44269504f;       // 1/sqrt(64) * log2(e), folded into Q

  for (int c = tid; c < 128 * 8; c += 512) {
    const int r = c >> 3, d8 = (c & 7) * 8;
    bf16x8 v = *(const bf16x8*)(qkv + (rowB + q0 + r) * (3 * EMB) + hoff + d8);
#pragma unroll
    for (int i = 0; i < 8; ++i) v[i] = (bf16)((float)v[i] * C1);
    *(bf16x8*)&Qs[r][d8] = v;
  }

  f32x4 zero = {0.f, 0.f, 0.f, 0.f};
  float l_run = 0.f;
  f32x4 o[4];  // O'[d][q]: col q=lc, row d=dt*16+quad*4+r
#pragma unroll
  for (int dt = 0; dt < 4; ++dt) o[dt] = zero;
  const int myq = q0 + wave * 16 + lc;

  for (int kt = 0; kt <= qt; ++kt) {
    const int kb = kt * 128;
    __syncthreads();
    for (int c = tid; c < 128 * 8; c += 512) {
      const int key = c >> 3, d8 = (c & 7) * 8;
      *(bf16x8*)&Ks[key][d8] =
          *(const bf16x8*)(qkv + (rowB + kb + key) * (3 * EMB) + EMB + hoff + d8);
    }
    for (int c = tid; c < 128 * 8; c += 512) {
      const int key = c >> 3, d8 = (c & 7) * 8;
      bf16x8 v = *(const bf16x8*)(qkv + (rowB + kb + key) * (3 * EMB) + 2 * EMB + hoff + d8);
#pragma unroll
      for (int i = 0; i < 8; ++i) Vt[d8 + i][key] = v[i];
    }
    __syncthreads();

    f32x4 s[8];
#pragma unroll
    for (int j = 0; j < 8; ++j) s[j] = zero;
#pragma unroll
    for (int ks = 0; ks < 2; ++ks) {
      bf16x8 bq = *(const bf16x8*)&Qs[wave * 16 + lc][ks * 32 + quad * 8];
#pragma unroll
      for (int j = 0; j < 8; ++j) {
        bf16x8 ak = *(const bf16x8*)&Ks[j * 16 + lc][ks * 32 + quad * 8];
        s[j] = __builtin_amdgcn_mfma_f32_16x16x32_bf16(ak, bq, s[j], 0, 0, 0);
      }
    }

    s16x4 pf[8];
    const bool diag = (kt == qt);
    if (diag) {
#pragma unroll
      for (int j = 0; j < 8; ++j) {
#pragma unroll
        for (int r = 0; r < 4; ++r) {
          const bool masked = (kb + j * 16 + quad * 4 + r > myq);
          const float p = masked ? 0.f : exp2f(s[j][r]);
          l_run += p;
          pf[j][r] = __builtin_bit_cast(short, (bf16)p);
        }
      }
    } else {
#pragma unroll
      for (int j = 0; j < 8; ++j) {
#pragma unroll
        for (int r = 0; r < 4; ++r) {
          const float p = exp2f(s[j][r]);
          l_run += p;
          pf[j][r] = __builtin_bit_cast(short, (bf16)p);
        }
      }
    }

#pragma unroll
    for (int j = 0; j < 8; ++j) {
#pragma unroll
      for (int dt = 0; dt < 4; ++dt) {
        s16x4 av = *(const s16x4*)&Vt[dt * 16 + lc][j * 16 + quad * 4];
        o[dt] = __builtin_amdgcn_mfma_f32_16x16x16bf16_1k(av, pf[j], o[dt], 0, 0, 0);
      }
    }
  }

  l_run += __shfl_xor(l_run, 16);
  l_run += __shfl_xor(l_run, 32);
  const float inv = 1.0f / l_run;
  __syncthreads();
#pragma unroll
  for (int dt = 0; dt < 4; ++dt)
#pragma unroll
    for (int r = 0; r < 4; ++r)
      Qs[wave * 16 + lc][dt * 16 + quad * 4 + r] = (bf16)(o[dt][r] * inv);
  __syncthreads();
  for (int c = tid; c < 128 * 8; c += 512) {
    const int r = c >> 3, d8 = (c & 7) * 8;
    *(bf16x8*)(outb + (rowB + q0 + r) * EMB + hoff + d8) = *(const bf16x8*)&Qs[r][d8];
  }
}

// ---------------- launch ----------------
extern "C" void kernel_launch(void* const* d_in, const int* in_sizes, int n_in,
                              void* d_out, int out_size, void* d_ws, size_t ws_size,
                              hipStream_t stream) {
  const float* x = (const float*)d_in[0];
  const float* Wattn = (const float*)d_in[1];
  const float* battn = (const float*)d_in[2];
  const float* Wproj = (const float*)d_in[3];
  const float* bproj = (const float*)d_in[4];
  float* out = (float*)d_out;

  const int M = in_sizes[0] / EMB;  // 8192
  const int Bn = M / T_SEQ;         // 8

  bf16* ws = (bf16*)d_ws;
  bf16* xb = ws;                                        // [M][768]
  bf16* Wt_attn = xb + (size_t)M * EMB;                 // [2304][768]
  bf16* Wt_proj = Wt_attn + (size_t)3 * EMB * EMB;      // [768][768]
  bf16* qkv = Wt_proj + (size_t)EMB * EMB;              // [M][2304]
  bf16* attnb = qkv + (size_t)M * 3 * EMB;              // [M][768]

  const int cvt_blocks = M * EMB / 8 / 256;             // 3072
  prep_k<<<cvt_blocks + 1728 + 576, 256, 0, stream>>>(x, xb, Wattn, Wt_attn, Wproj, Wt_proj);

  gemm_bt<0><<<dim3(3 * EMB / 128, M / 128), 256, 0, stream>>>(
      xb, Wt_attn, battn, qkv, nullptr, M, 3 * EMB, EMB);

  attn_k<<<dim3((T_SEQ / 128) * Bn * HEADS), 512, 0, stream>>>(qkv, attnb);

  gemm_bt<1><<<dim3(EMB / 128, M / 128), 256, 0, stream>>>(
      attnb, Wt_proj, bproj, nullptr, out, M, EMB, EMB);
}

// Round 9
// 179.823 us; speedup vs baseline: 1.0694x; 1.0694x over previous
//
#include <hip/hip_runtime.h>
#include <hip/hip_bf16.h>
#include <math.h>

typedef __bf16 bf16;
typedef __attribute__((ext_vector_type(8))) __bf16 bf16x8;
typedef __attribute__((ext_vector_type(4))) short s16x4;
typedef __attribute__((ext_vector_type(4))) float f32x4;

#define EMB 768
#define T_SEQ 1024
#define HEADS 12
#define HDIM 64

// ---------------- fused prep: x fp32->bf16, W_attn / W_proj transpose+cvt ----------------
__global__ void prep_k(const float* __restrict__ x, bf16* __restrict__ xb,
                       const float* __restrict__ Wa, bf16* __restrict__ Wta,
                       const float* __restrict__ Wp, bf16* __restrict__ Wtp) {
  __shared__ float tile[32][33];
  const int blk = blockIdx.x, tid = threadIdx.x;
  if (blk < 3072) {
    const size_t i = (size_t)blk * 256 + tid;
    const float4* p = (const float4*)(x + i * 8);
    const float4 a = p[0], b = p[1];
    bf16x8 v;
    v[0] = (bf16)a.x; v[1] = (bf16)a.y; v[2] = (bf16)a.z; v[3] = (bf16)a.w;
    v[4] = (bf16)b.x; v[5] = (bf16)b.y; v[6] = (bf16)b.z; v[7] = (bf16)b.w;
    *(bf16x8*)(xb + i * 8) = v;
    return;
  }
  const float* in;
  bf16* out;
  int C, t;
  if (blk < 3072 + 1728) { in = Wa; out = Wta; C = 3 * EMB; t = blk - 3072; }
  else                   { in = Wp; out = Wtp; C = EMB;     t = blk - 4800; }
  const int R = EMB;
  const int c0 = (t % (C / 32)) * 32, r0 = (t / (C / 32)) * 32;
  const int tx = tid & 31, ty = tid >> 5;
  for (int i = ty; i < 32; i += 8)
    tile[i][tx] = in[(size_t)(r0 + i) * C + c0 + tx];
  __syncthreads();
  for (int i = ty; i < 32; i += 8)
    out[(size_t)(c0 + i) * R + r0 + tx] = (bf16)tile[tx][i];
}

// ---------------- GEMM: C[M][N] = A[M][K] @ Bt[N][K]^T + bias, BK=64 (2x32), R7 body ----------------
// 1-D grid, XCD-aware placement: XCD k owns M-tiles [k*8, k*8+8) and sweeps N-tiles
// (x-outer, y-inner per XCD). Per-XCD L2 set = 8 A-tiles (1.57 MB, persistent) +
// current W-tile (196 KB) -> A fetched once/device, W once/XCD.
// NXT = number of N-tiles (grid = NXT * 64 blocks, M fixed at 8192 -> 64 M-tiles).
template <int MODE, int NXT>
__global__ __launch_bounds__(256) void gemm_bt(
    const bf16* __restrict__ A, const bf16* __restrict__ Bt, const float* __restrict__ bias,
    bf16* __restrict__ Cb, float* __restrict__ Cf, int M, int N, int K) {
  __shared__ __align__(16) bf16 As0[128 * 32];
  __shared__ __align__(16) bf16 As1[128 * 32];
  __shared__ __align__(16) bf16 Bs0[128 * 32];
  __shared__ __align__(16) bf16 Bs1[128 * 32];
  const int lane = threadIdx.x & 63;
  const int wave = threadIdx.x >> 6;
  const int quad = lane >> 4, lc = lane & 15;

  // XCD-aware tile assignment (dispatch round-robins blockIdx % 8 across XCDs)
  const int xcd = blockIdx.x & 7;
  const int idx = blockIdx.x >> 3;           // 0 .. NXT*8-1 per XCD
  const int m0 = (xcd * 8 + (idx & 7)) * 128;
  const int n0 = (idx >> 3) * 128;           // x-outer: W-tile streams, A-tiles persist

  const int wm = (wave >> 1) * 64, wn = (wave & 1) * 64;
  const int srow = lane >> 2;
  const int skk = (lane & 3) * 8;

  f32x4 zero = {0.f, 0.f, 0.f, 0.f};
  f32x4 acc[4][4];
#pragma unroll
  for (int i = 0; i < 4; ++i)
#pragma unroll
    for (int j = 0; j < 4; ++j) acc[i][j] = zero;

  for (int k0 = 0; k0 < K; k0 += 64) {
    __syncthreads();
#pragma unroll
    for (int c = wave; c < 8; c += 4) {
      const bf16* gA = A + (size_t)(m0 + c * 16 + srow) * K + k0 + skk;
      const bf16* gB = Bt + (size_t)(n0 + c * 16 + srow) * K + k0 + skk;
      __builtin_amdgcn_global_load_lds((const __attribute__((address_space(1))) void*)gA,
                                       (__attribute__((address_space(3))) void*)(As0 + c * 512), 16, 0, 0);
      __builtin_amdgcn_global_load_lds((const __attribute__((address_space(1))) void*)(gA + 32),
                                       (__attribute__((address_space(3))) void*)(As1 + c * 512), 16, 0, 0);
      __builtin_amdgcn_global_load_lds((const __attribute__((address_space(1))) void*)gB,
                                       (__attribute__((address_space(3))) void*)(Bs0 + c * 512), 16, 0, 0);
      __builtin_amdgcn_global_load_lds((const __attribute__((address_space(1))) void*)(gB + 32),
                                       (__attribute__((address_space(3))) void*)(Bs1 + c * 512), 16, 0, 0);
    }
    __syncthreads();
    {
      bf16x8 af[4], bfr[4];
#pragma unroll
      for (int t = 0; t < 4; ++t) af[t] = *(const bf16x8*)&As0[(wm + t * 16 + lc) * 32 + quad * 8];
#pragma unroll
      for (int t = 0; t < 4; ++t) bfr[t] = *(const bf16x8*)&Bs0[(wn + t * 16 + lc) * 32 + quad * 8];
#pragma unroll
      for (int tm = 0; tm < 4; ++tm)
#pragma unroll
        for (int tn = 0; tn < 4; ++tn)
          acc[tm][tn] = __builtin_amdgcn_mfma_f32_16x16x32_bf16(af[tm], bfr[tn], acc[tm][tn], 0, 0, 0);
    }
    {
      bf16x8 af[4], bfr[4];
#pragma unroll
      for (int t = 0; t < 4; ++t) af[t] = *(const bf16x8*)&As1[(wm + t * 16 + lc) * 32 + quad * 8];
#pragma unroll
      for (int t = 0; t < 4; ++t) bfr[t] = *(const bf16x8*)&Bs1[(wn + t * 16 + lc) * 32 + quad * 8];
#pragma unroll
      for (int tm = 0; tm < 4; ++tm)
#pragma unroll
        for (int tn = 0; tn < 4; ++tn)
          acc[tm][tn] = __builtin_amdgcn_mfma_f32_16x16x32_bf16(af[tm], bfr[tn], acc[tm][tn], 0, 0, 0);
    }
  }

#pragma unroll
  for (int tm = 0; tm < 4; ++tm) {
#pragma unroll
    for (int tn = 0; tn < 4; ++tn) {
      const int col = n0 + wn + tn * 16 + lc;
      const float bv = bias[col];
#pragma unroll
      for (int r = 0; r < 4; ++r) {
        const int row = m0 + wm + tm * 16 + quad * 4 + r;
        const float v = acc[tm][tn][r] + bv;
        if (MODE == 0) Cb[(size_t)row * N + col] = (bf16)v;
        else           Cf[(size_t)row * N + col] = v;
      }
    }
  }
}

// ---------------- causal flash attention, transposed-score, no-max exp2 softmax ----------------
// qkv: [B*T][2304] rows (q|k|v); outb: [B*T][768]
__global__ __launch_bounds__(512, 4) void attn_k(const bf16* __restrict__ qkv,
                                                 bf16* __restrict__ outb) {
  __shared__ __align__(16) bf16 Qs[128][72];   // [q][d], pre-scaled by log2(e)/8; reused for O out
  __shared__ __align__(16) bf16 Ks[128][72];   // [key][d]
  __shared__ __align__(16) bf16 Vt[64][132];   // V^T [d][key]

  const int lane = threadIdx.x & 63;
  const int wave = threadIdx.x >> 6;           // 0..7, each owns 16 q rows
  const int quad = lane >> 4, lc = lane & 15;
  const int flat = blockIdx.x;
  const int bh = flat % (HEADS * 8);
  const int qt = 7 - flat / (HEADS * 8);
  const int h = bh % HEADS;
  const int b = bh / HEADS;
  const int q0 = qt * 128;
  const size_t rowB = (size_t)b * T_SEQ;
  const int hoff = h * HDIM;
  const int tid = threadIdx.x;
  const float C1 = 0.125f * 1.44269504f;       // 1/sqrt(64) * log2(e), folded into Q

  for (int c = tid; c < 128 * 8; c += 512) {
    const int r = c >> 3, d8 = (c & 7) * 8;
    bf16x8 v = *(const bf16x8*)(qkv + (rowB + q0 + r) * (3 * EMB) + hoff + d8);
#pragma unroll
    for (int i = 0; i < 8; ++i) v[i] = (bf16)((float)v[i] * C1);
    *(bf16x8*)&Qs[r][d8] = v;
  }

  f32x4 zero = {0.f, 0.f, 0.f, 0.f};
  float l_run = 0.f;
  f32x4 o[4];  // O'[d][q]: col q=lc, row d=dt*16+quad*4+r
#pragma unroll
  for (int dt = 0; dt < 4; ++dt) o[dt] = zero;
  const int myq = q0 + wave * 16 + lc;

  for (int kt = 0; kt <= qt; ++kt) {
    const int kb = kt * 128;
    __syncthreads();
    for (int c = tid; c < 128 * 8; c += 512) {
      const int key = c >> 3, d8 = (c & 7) * 8;
      *(bf16x8*)&Ks[key][d8] =
          *(const bf16x8*)(qkv + (rowB + kb + key) * (3 * EMB) + EMB + hoff + d8);
    }
    for (int c = tid; c < 128 * 8; c += 512) {
      const int key = c >> 3, d8 = (c & 7) * 8;
      bf16x8 v = *(const bf16x8*)(qkv + (rowB + kb + key) * (3 * EMB) + 2 * EMB + hoff + d8);
#pragma unroll
      for (int i = 0; i < 8; ++i) Vt[d8 + i][key] = v[i];
    }
    __syncthreads();

    f32x4 s[8];
#pragma unroll
    for (int j = 0; j < 8; ++j) s[j] = zero;
#pragma unroll
    for (int ks = 0; ks < 2; ++ks) {
      bf16x8 bq = *(const bf16x8*)&Qs[wave * 16 + lc][ks * 32 + quad * 8];
#pragma unroll
      for (int j = 0; j < 8; ++j) {
        bf16x8 ak = *(const bf16x8*)&Ks[j * 16 + lc][ks * 32 + quad * 8];
        s[j] = __builtin_amdgcn_mfma_f32_16x16x32_bf16(ak, bq, s[j], 0, 0, 0);
      }
    }

    s16x4 pf[8];
    const bool diag = (kt == qt);
    if (diag) {
#pragma unroll
      for (int j = 0; j < 8; ++j) {
#pragma unroll
        for (int r = 0; r < 4; ++r) {
          const bool masked = (kb + j * 16 + quad * 4 + r > myq);
          const float p = masked ? 0.f : exp2f(s[j][r]);
          l_run += p;
          pf[j][r] = __builtin_bit_cast(short, (bf16)p);
        }
      }
    } else {
#pragma unroll
      for (int j = 0; j < 8; ++j) {
#pragma unroll
        for (int r = 0; r < 4; ++r) {
          const float p = exp2f(s[j][r]);
          l_run += p;
          pf[j][r] = __builtin_bit_cast(short, (bf16)p);
        }
      }
    }

#pragma unroll
    for (int j = 0; j < 8; ++j) {
#pragma unroll
      for (int dt = 0; dt < 4; ++dt) {
        s16x4 av = *(const s16x4*)&Vt[dt * 16 + lc][j * 16 + quad * 4];
        o[dt] = __builtin_amdgcn_mfma_f32_16x16x16bf16_1k(av, pf[j], o[dt], 0, 0, 0);
      }
    }
  }

  l_run += __shfl_xor(l_run, 16);
  l_run += __shfl_xor(l_run, 32);
  const float inv = 1.0f / l_run;
  __syncthreads();
#pragma unroll
  for (int dt = 0; dt < 4; ++dt)
#pragma unroll
    for (int r = 0; r < 4; ++r)
      Qs[wave * 16 + lc][dt * 16 + quad * 4 + r] = (bf16)(o[dt][r] * inv);
  __syncthreads();
  for (int c = tid; c < 128 * 8; c += 512) {
    const int r = c >> 3, d8 = (c & 7) * 8;
    *(bf16x8*)(outb + (rowB + q0 + r) * EMB + hoff + d8) = *(const bf16x8*)&Qs[r][d8];
  }
}

// ---------------- launch ----------------
extern "C" void kernel_launch(void* const* d_in, const int* in_sizes, int n_in,
                              void* d_out, int out_size, void* d_ws, size_t ws_size,
                              hipStream_t stream) {
  const float* x = (const float*)d_in[0];
  const float* Wattn = (const float*)d_in[1];
  const float* battn = (const float*)d_in[2];
  const float* Wproj = (const float*)d_in[3];
  const float* bproj = (const float*)d_in[4];
  float* out = (float*)d_out;

  const int M = in_sizes[0] / EMB;  // 8192
  const int Bn = M / T_SEQ;         // 8

  bf16* ws = (bf16*)d_ws;
  bf16* xb = ws;                                        // [M][768]
  bf16* Wt_attn = xb + (size_t)M * EMB;                 // [2304][768]
  bf16* Wt_proj = Wt_attn + (size_t)3 * EMB * EMB;      // [768][768]
  bf16* qkv = Wt_proj + (size_t)EMB * EMB;              // [M][2304]
  bf16* attnb = qkv + (size_t)M * 3 * EMB;              // [M][768]

  const int cvt_blocks = M * EMB / 8 / 256;             // 3072
  prep_k<<<cvt_blocks + 1728 + 576, 256, 0, stream>>>(x, xb, Wattn, Wt_attn, Wproj, Wt_proj);

  gemm_bt<0, 18><<<18 * 64, 256, 0, stream>>>(
      xb, Wt_attn, battn, qkv, nullptr, M, 3 * EMB, EMB);

  attn_k<<<dim3((T_SEQ / 128) * Bn * HEADS), 512, 0, stream>>>(qkv, attnb);

  gemm_bt<1, 6><<<6 * 64, 256, 0, stream>>>(
      attnb, Wt_proj, bproj, nullptr, out, M, EMB, EMB);
}